// Round 3
// baseline (320.334 us; speedup 1.0000x reference)
//
#include <hip/hip_runtime.h>

typedef unsigned short u16;
typedef unsigned int u32;
typedef __attribute__((ext_vector_type(8))) short bf16x8;
typedef __attribute__((ext_vector_type(4))) float f32x4;
typedef __attribute__((ext_vector_type(2))) float f32x2;

#define NND 50000
#define NE 800000
#define NH 8
#define ND 32
#define NTY 5

__device__ inline u16 f2bf(float x){
  u32 u = __float_as_uint(x);
  return (u16)((u + 0x7FFFu + ((u >> 16) & 1u)) >> 16);
}

// ---------------- W pre-convert: fc_w fp32 -> bf16 once
__global__ __launch_bounds__(256) void wcvt_k(const float* __restrict__ W,
                                              u16* __restrict__ Wb){
  int i = (blockIdx.x * 256 + threadIdx.x) * 4;
  f32x4 v = __builtin_nontemporal_load((const f32x4*)(W + i));
  ushort4 h = make_ushort4(f2bf(v[0]), f2bf(v[1]), f2bf(v[2]), f2bf(v[3]));
  *(ushort4*)(Wb + i) = h;
}

// ---------------- GEMM: feat[M,256] @ fc_w[256,256]^T -> feat_src bf16, stored
// HEAD-MAJOR: fsrc[h][node][32] (h = col>>5). Each head region is 3.2 MB --
// sized so ONE XCD's L2 (4 MB) can hold it during agg's head-per-XCD pass.
// 512 threads, block tile 128m x 256n, A nt-loaded once, bf16 at staging,
// XOR-swizzled LDS (ds_read_b128 2-way = free). fsrc stored non-temporal.
__global__ __launch_bounds__(512, 4) void gemm_k(const float* __restrict__ A,
                                                 const u16* __restrict__ Wb,
                                                 u16* __restrict__ C, int M){
  __shared__ u16 As[128 * 64];  // 16KB: addr(r,ch) u16s = r*64 + ((ch^(r&7))*8)
  __shared__ u16 Ws[256 * 64];  // 32KB: addr(n,ch) u16s = n*64 + ((ch^(n&7))*8)
  const int tid  = threadIdx.x;
  const int m0   = blockIdx.x * 128;
  const int lane = tid & 63, wid = tid >> 6;
  const int wm = (wid >> 2) * 64, wn = (wid & 3) * 64;
  const int ml = lane & 15, quad = lane >> 4;

  f32x4 acc[4][4] = {};

  const int ra = tid >> 2, ca0 = (tid & 3) * 2;
  int rag = m0 + ra; if (rag >= M) rag = M - 1;   // clamp: garbage rows never stored
  const float* aRow = A + (size_t)rag * 256;
  const int rw = tid >> 1, hw = tid & 1;
  const u16* wRow = Wb + (size_t)rw * 256;

  for (int k0 = 0; k0 < 256; k0 += 64){
    #pragma unroll
    for (int q = 0; q < 2; q++){
      int ch = ca0 + q;
      f32x4 v0 = __builtin_nontemporal_load((const f32x4*)(aRow + k0 + ch * 8));
      f32x4 v1 = __builtin_nontemporal_load((const f32x4*)(aRow + k0 + ch * 8 + 4));
      ushort4 h0 = make_ushort4(f2bf(v0[0]), f2bf(v0[1]), f2bf(v0[2]), f2bf(v0[3]));
      ushort4 h1 = make_ushort4(f2bf(v1[0]), f2bf(v1[1]), f2bf(v1[2]), f2bf(v1[3]));
      u16* p = As + ra * 64 + ((ch ^ (ra & 7)) * 8);
      *(ushort4*)p = h0;
      *(ushort4*)(p + 4) = h1;
    }
    #pragma unroll
    for (int q = 0; q < 4; q++){
      int ch = hw * 4 + q;
      uint4 wv = *(const uint4*)(wRow + k0 + ch * 8);
      *(uint4*)(Ws + rw * 64 + ((ch ^ (rw & 7)) * 8)) = wv;
    }
    __syncthreads();
    #pragma unroll
    for (int kk = 0; kk < 64; kk += 32){
      bf16x8 af[4], wf[4];
      const int cA = (kk >> 3) + quad;
      #pragma unroll
      for (int t = 0; t < 4; t++){
        int r = wm + t * 16 + ml;
        af[t] = *(const bf16x8*)(As + r * 64 + ((cA ^ (r & 7)) * 8));
      }
      #pragma unroll
      for (int t = 0; t < 4; t++){
        int n = wn + t * 16 + ml;
        wf[t] = *(const bf16x8*)(Ws + n * 64 + ((cA ^ (n & 7)) * 8));
      }
      #pragma unroll
      for (int i = 0; i < 4; i++)
        #pragma unroll
        for (int j = 0; j < 4; j++)
          acc[i][j] = __builtin_amdgcn_mfma_f32_16x16x32_bf16(af[i], wf[j], acc[i][j], 0, 0, 0);
    }
    __syncthreads();
  }
  // head-major store: wave's cols wn..wn+63 = heads hb, hb+1; col within = (j&1)*16+ml
  const int hb = wn >> 5;
  #pragma unroll
  for (int i = 0; i < 4; i++){
    #pragma unroll
    for (int rr = 0; rr < 4; rr++){
      int row = m0 + wm + i * 16 + quad * 4 + rr;
      if (row < M){
        u16* r0 = C + ((size_t)hb       * NND + row) * 32 + ml;
        u16* r1 = C + ((size_t)(hb + 1) * NND + row) * 32 + ml;
        __builtin_nontemporal_store(f2bf(acc[i][0][rr]), r0);
        __builtin_nontemporal_store(f2bf(acc[i][1][rr]), r0 + 16);
        __builtin_nontemporal_store(f2bf(acc[i][2][rr]), r1);
        __builtin_nontemporal_store(f2bf(acc[i][3][rr]), r1 + 16);
      }
    }
  }
}

// ---------------- count: per-dst degree + per-edge rank (ONE atomic per edge)
__global__ __launch_bounds__(256) void count_k(const int* __restrict__ dst,
                                               int* __restrict__ deg,
                                               int* __restrict__ epos){
  int e = blockIdx.x * 256 + threadIdx.x;
  if (e < NE) epos[e] = atomicAdd(&deg[dst[e]], 1);
}

// ---------------- scan degrees -> block-local exclusive offsets + block sums
__global__ __launch_bounds__(256) void scan1_k(const int* __restrict__ deg,
                                               int* __restrict__ offs,
                                               int* __restrict__ bsum){
  __shared__ int lds[256];
  int b = blockIdx.x, tid = threadIdx.x;
  int base = b * 1024 + tid * 4;
  int d[4]; int tsum = 0;
  #pragma unroll
  for (int j = 0; j < 4; j++){
    int node = base + j;
    int v = (node < NND) ? deg[node] : 0;
    d[j] = tsum; tsum += v;
  }
  lds[tid] = tsum; __syncthreads();
  for (int off = 1; off < 256; off <<= 1){
    int v = (tid >= off) ? lds[tid - off] : 0;
    __syncthreads();
    lds[tid] += v;
    __syncthreads();
  }
  int excl = lds[tid] - tsum;
  #pragma unroll
  for (int j = 0; j < 4; j++)
    if (base + j < NND) offs[base + j] = excl + d[j];
  if (tid == 255) bsum[b] = lds[tid];
}

__global__ __launch_bounds__(64) void scan2_k(const int* __restrict__ bsum,
                                              int* __restrict__ bbase, int nb){
  __shared__ int l[64];
  int tid = threadIdx.x;
  int v = (tid < nb) ? bsum[tid] : 0;
  l[tid] = v; __syncthreads();
  for (int off = 1; off < 64; off <<= 1){
    int u = (tid >= off) ? l[tid - off] : 0;
    __syncthreads();
    l[tid] += u;
    __syncthreads();
  }
  bbase[tid] = l[tid] - v;
}

// ---------------- scatter edges into CSR (NO atomics)
// csr entry = (src << 7) | etype  (src < 50000 < 2^16, etype < 8)
__global__ __launch_bounds__(256) void scatter_k(const int* __restrict__ dst,
                                                 const int* __restrict__ src,
                                                 const int* __restrict__ ef,
                                                 const int* __restrict__ epos,
                                                 const int* __restrict__ offs,
                                                 const int* __restrict__ bbase,
                                                 int* __restrict__ csr){
  int e = blockIdx.x * 256 + threadIdx.x;
  if (e >= NE) return;
  int d = dst[e];
  int pos = offs[d] + bbase[d >> 10] + epos[e];
  csr[pos] = (src[e] << 7) | ef[e];
}

// ---------------- attn output: attn[e,h] = wl[type,h] * rdh[h][dst]
// (rdh produced by agg_k, which runs first). nt-stores (write-once output).
__global__ __launch_bounds__(256) void attn_k(const int* __restrict__ dst,
                                              const int* __restrict__ ef,
                                              const float* __restrict__ rdh,
                                              const float* __restrict__ emb,
                                              float* __restrict__ attn){
  __shared__ float wl[40];
  int tid = threadIdx.x;
  if (tid < 40){
    int t = tid >> 3, h = tid & 7;
    float m = emb[h];
    for (int tt = 1; tt < NTY; ++tt) m = fmaxf(m, emb[tt * 8 + h]);
    wl[tid] = expf(emb[t * 8 + h] - m);
  }
  __syncthreads();
  int e = blockIdx.x * 256 + tid;
  if (e >= NE) return;
  int d = dst[e], t = ef[e];
  const float* wr = wl + t * 8;
  f32x4 o0, o1;
  #pragma unroll
  for (int h = 0; h < 8; h++){
    float r = rdh[(size_t)h * NND + d];
    float v = wr[h] * r;
    if (h < 4) o0[h] = v; else o1[h - 4] = v;
  }
  __builtin_nontemporal_store(o0, (f32x4*)(attn + (size_t)e * 8));
  __builtin_nontemporal_store(o1, (f32x4*)(attn + (size_t)e * 8 + 4));
}

// ---------------- aggregation: rd cancels -> rst = (Σ w·fsrc) / (Σ w).
// 8 HEAD-PASSES PINNED TO XCDs: head = blockIdx & 7 = XCD (HW round-robins
// consecutive workgroups across the 8 XCDs). Each XCD gathers ONLY its own
// 3.2 MB head-major fsrc region, which FITS its 4 MB L2 -> gather fill drops
// to compulsory (~25.6 MB total vs 132 MB round-2). csr/offs/deg are read
// exactly once per XCD now (zero reuse) -> nt-loads so they don't evict the
// resident fsrc slice. 4 lanes/node x 16B = 64B/edge-pass; total lane-gathers,
// unpack VALU and FLOPs identical to the quarter scheme (8 passes x half bytes).
__device__ inline void acc8(uint4 v, float wt, f32x2* a){
  f32x2 w2; w2.x = wt; w2.y = wt;
  f32x2 t0; t0.x = __uint_as_float(v.x << 16); t0.y = __uint_as_float(v.x & 0xFFFF0000u);
  f32x2 t1; t1.x = __uint_as_float(v.y << 16); t1.y = __uint_as_float(v.y & 0xFFFF0000u);
  f32x2 t2; t2.x = __uint_as_float(v.z << 16); t2.y = __uint_as_float(v.z & 0xFFFF0000u);
  f32x2 t3; t3.x = __uint_as_float(v.w << 16); t3.y = __uint_as_float(v.w & 0xFFFF0000u);
  a[0] += w2 * t0; a[1] += w2 * t1; a[2] += w2 * t2; a[3] += w2 * t3;
}

#define NBAGG ((NND + 63) / 64)   // 782 node-blocks per head

__global__ __launch_bounds__(256) void agg_k(const u16* __restrict__ fsrc,
                                             const int* __restrict__ csr,
                                             const int* __restrict__ offs,
                                             const int* __restrict__ bbase,
                                             const int* __restrict__ deg,
                                             const float* __restrict__ emb,
                                             float* __restrict__ rst,
                                             float* __restrict__ rdh){
  __shared__ float wl5[8];   // exp(emb[t,h]-max_t) for this block's head
  const int tid = threadIdx.x;
  const int h  = blockIdx.x & 7;   // head == XCD
  const int nb = blockIdx.x >> 3;  // node-block within head
  if (tid < NTY){
    float m = emb[h];
    for (int tt = 1; tt < NTY; ++tt) m = fmaxf(m, emb[tt * 8 + h]);
    wl5[tid] = expf(emb[tid * 8 + h] - m);
  }
  __syncthreads();
  int node = nb * 64 + (tid >> 2);
  if (node >= NND) return;
  const int sl = tid & 2 ? (tid & 3) : (tid & 3);  // lane within node (0..3)
  const int sl4 = tid & 3;
  const u16* hbase = fsrc + (size_t)h * (NND * 32) + sl4 * 8;
  int s = offs[node] + bbase[node >> 10];
  int e = s + deg[node];
  f32x2 a[4]; a[0] = 0.f; a[1] = 0.f; a[2] = 0.f; a[3] = 0.f;
  float ss = 0.f;
  int i = s;
  for (; i + 3 < e; i += 4){
    int p0 = __builtin_nontemporal_load(csr + i);
    int p1 = __builtin_nontemporal_load(csr + i + 1);
    int p2 = __builtin_nontemporal_load(csr + i + 2);
    int p3 = __builtin_nontemporal_load(csr + i + 3);
    uint4 v0 = *(const uint4*)(hbase + ((size_t)(p0 >> 7) << 5));
    uint4 v1 = *(const uint4*)(hbase + ((size_t)(p1 >> 7) << 5));
    uint4 v2 = *(const uint4*)(hbase + ((size_t)(p2 >> 7) << 5));
    uint4 v3 = *(const uint4*)(hbase + ((size_t)(p3 >> 7) << 5));
    float w0 = wl5[p0 & 7];
    float w1 = wl5[p1 & 7];
    float w2 = wl5[p2 & 7];
    float w3 = wl5[p3 & 7];
    acc8(v0, w0, a); acc8(v1, w1, a); acc8(v2, w2, a); acc8(v3, w3, a);
    ss += (w0 + w1) + (w2 + w3);
  }
  for (; i < e; i++){
    int p0 = __builtin_nontemporal_load(csr + i);
    uint4 v0 = *(const uint4*)(hbase + ((size_t)(p0 >> 7) << 5));
    float w0 = wl5[p0 & 7];
    acc8(v0, w0, a);
    ss += w0;
  }
  float inv = 1.0f / (ss + 1e-12f);
  f32x4 o0, o1;
  o0[0] = a[0].x*inv; o0[1] = a[0].y*inv; o0[2] = a[1].x*inv; o0[3] = a[1].y*inv;
  o1[0] = a[2].x*inv; o1[1] = a[2].y*inv; o1[2] = a[3].x*inv; o1[3] = a[3].y*inv;
  float* orow = rst + (size_t)node * 256 + h * 32 + sl4 * 8;
  __builtin_nontemporal_store(o0, (f32x4*)orow);
  __builtin_nontemporal_store(o1, (f32x4*)(orow + 4));
  // rdh for attn_k: one lane per node writes this head's 1/denominator.
  if (sl4 == 0)
    __builtin_nontemporal_store(inv, rdh + (size_t)h * NND + node);
}

extern "C" void kernel_launch(void* const* d_in, const int* in_sizes, int n_in,
                              void* d_out, int out_size, void* d_ws, size_t ws_size,
                              hipStream_t stream) {
  const float* feat = (const float*)d_in[0];
  const float* fcw  = (const float*)d_in[1];
  const float* emb  = (const float*)d_in[2];
  const int*   ef   = (const int*)d_in[3];
  const int*   src  = (const int*)d_in[4];
  const int*   dst  = (const int*)d_in[5];

  float* rst  = (float*)d_out;                         // [50000, 8, 32]
  float* attn = (float*)d_out + (size_t)NND * NH * ND; // [800000, 8]

  char* ws = (char*)d_ws;
  size_t o = 0;
  u16* fsrc    = (u16*)(ws + o);   o += (size_t)NND * 256 * 2;   // 25.6 MB (head-major)
  int* csr     = (int*)(ws + o);   o += (size_t)NE * 4;          // 3.2 MB
  int* epos    = (int*)(ws + o);   o += (size_t)NE * 4;          // 3.2 MB
  int* offs    = (int*)(ws + o);   o += 200064;
  int* deg     = (int*)(ws + o);   o += 200064;
  float* rdh   = (float*)(ws + o); o += (size_t)NND * NH * 4;    // 1.6 MB [8][NND]
  u16* wb      = (u16*)(ws + o);   o += (size_t)256 * 256 * 2;   // 128 KB
  int* bsum    = (int*)(ws + o);   o += 256;
  int* bbase   = (int*)(ws + o);   o += 256;

  hipMemsetAsync(deg, 0, (size_t)NND * 4, stream);

  wcvt_k<<<64, 256, 0, stream>>>(fcw, wb);
  gemm_k<<<391, 512, 0, stream>>>(feat, wb, fsrc, NND);
  count_k<<<(NE + 255) / 256, 256, 0, stream>>>(dst, deg, epos);
  scan1_k<<<(NND + 1023) / 1024, 256, 0, stream>>>(deg, offs, bsum);
  scan2_k<<<1, 64, 0, stream>>>(bsum, bbase, (NND + 1023) / 1024);
  scatter_k<<<(NE + 255) / 256, 256, 0, stream>>>(dst, src, ef, epos, offs, bbase, csr);
  agg_k<<<8 * NBAGG, 256, 0, stream>>>(fsrc, csr, offs, bbase, deg, emb, rst, rdh);
  attn_k<<<(NE + 255) / 256, 256, 0, stream>>>(dst, ef, rdh, emb, attn);
}

// Round 4
// 263.164 us; speedup vs baseline: 1.2172x; 1.2172x over previous
//
#include <hip/hip_runtime.h>

typedef unsigned short u16;
typedef unsigned int u32;
typedef __attribute__((ext_vector_type(8))) short bf16x8;
typedef __attribute__((ext_vector_type(4))) float f32x4;
typedef __attribute__((ext_vector_type(2))) float f32x2;

#define NND 50000
#define NE 800000
#define NH 8
#define ND 32
#define NTY 5
#define NV (NND * 4)              // virtual nodes: (node, src-quarter)
#define SQSH 14                   // src-quarter = src >> 14 (regions of 16384 src)

__device__ inline u16 f2bf(float x){
  u32 u = __float_as_uint(x);
  return (u16)((u + 0x7FFFu + ((u >> 16) & 1u)) >> 16);
}

// ---------------- W pre-convert: fc_w fp32 -> bf16 once
__global__ __launch_bounds__(256) void wcvt_k(const float* __restrict__ W,
                                              u16* __restrict__ Wb){
  int i = (blockIdx.x * 256 + threadIdx.x) * 4;
  f32x4 v = __builtin_nontemporal_load((const f32x4*)(W + i));
  ushort4 h = make_ushort4(f2bf(v[0]), f2bf(v[1]), f2bf(v[2]), f2bf(v[3]));
  *(ushort4*)(Wb + i) = h;
}

// ---------------- GEMM: feat[M,256] @ fc_w[256,256]^T -> feat_src bf16, stored
// PAIR-QUARTER-MAJOR: fsrc[q][node][64] (q = col>>6, heads 2q,2q+1) -> 128B
// rows so agg's gather is one full cache line per edge (request-rate floor).
// 512 threads, 128m x 256n tile, A nt-loaded once, bf16 at staging,
// XOR-swizzled LDS (ds_read_b128 2-way = free). fsrc stored non-temporal.
__global__ __launch_bounds__(512, 4) void gemm_k(const float* __restrict__ A,
                                                 const u16* __restrict__ Wb,
                                                 u16* __restrict__ C, int M){
  __shared__ u16 As[128 * 64];  // 16KB: addr(r,ch) u16s = r*64 + ((ch^(r&7))*8)
  __shared__ u16 Ws[256 * 64];  // 32KB: addr(n,ch) u16s = n*64 + ((ch^(n&7))*8)
  const int tid  = threadIdx.x;
  const int m0   = blockIdx.x * 128;
  const int lane = tid & 63, wid = tid >> 6;
  const int wm = (wid >> 2) * 64, wn = (wid & 3) * 64;
  const int ml = lane & 15, quad = lane >> 4;

  f32x4 acc[4][4] = {};

  const int ra = tid >> 2, ca0 = (tid & 3) * 2;
  int rag = m0 + ra; if (rag >= M) rag = M - 1;   // clamp: garbage rows never stored
  const float* aRow = A + (size_t)rag * 256;
  const int rw = tid >> 1, hw = tid & 1;
  const u16* wRow = Wb + (size_t)rw * 256;

  for (int k0 = 0; k0 < 256; k0 += 64){
    #pragma unroll
    for (int q = 0; q < 2; q++){
      int ch = ca0 + q;
      f32x4 v0 = __builtin_nontemporal_load((const f32x4*)(aRow + k0 + ch * 8));
      f32x4 v1 = __builtin_nontemporal_load((const f32x4*)(aRow + k0 + ch * 8 + 4));
      ushort4 h0 = make_ushort4(f2bf(v0[0]), f2bf(v0[1]), f2bf(v0[2]), f2bf(v0[3]));
      ushort4 h1 = make_ushort4(f2bf(v1[0]), f2bf(v1[1]), f2bf(v1[2]), f2bf(v1[3]));
      u16* p = As + ra * 64 + ((ch ^ (ra & 7)) * 8);
      *(ushort4*)p = h0;
      *(ushort4*)(p + 4) = h1;
    }
    #pragma unroll
    for (int q = 0; q < 4; q++){
      int ch = hw * 4 + q;
      uint4 wv = *(const uint4*)(wRow + k0 + ch * 8);
      *(uint4*)(Ws + rw * 64 + ((ch ^ (rw & 7)) * 8)) = wv;
    }
    __syncthreads();
    #pragma unroll
    for (int kk = 0; kk < 64; kk += 32){
      bf16x8 af[4], wf[4];
      const int cA = (kk >> 3) + quad;
      #pragma unroll
      for (int t = 0; t < 4; t++){
        int r = wm + t * 16 + ml;
        af[t] = *(const bf16x8*)(As + r * 64 + ((cA ^ (r & 7)) * 8));
      }
      #pragma unroll
      for (int t = 0; t < 4; t++){
        int n = wn + t * 16 + ml;
        wf[t] = *(const bf16x8*)(Ws + n * 64 + ((cA ^ (n & 7)) * 8));
      }
      #pragma unroll
      for (int i = 0; i < 4; i++)
        #pragma unroll
        for (int j = 0; j < 4; j++)
          acc[i][j] = __builtin_amdgcn_mfma_f32_16x16x32_bf16(af[i], wf[j], acc[i][j], 0, 0, 0);
    }
    __syncthreads();
  }
  // pair-quarter-major store: wave's 64 cols live entirely in quarter wn>>6
  const size_t qoff = (size_t)(wn >> 6) * NND * 64;
  #pragma unroll
  for (int i = 0; i < 4; i++){
    #pragma unroll
    for (int rr = 0; rr < 4; rr++){
      int row = m0 + wm + i * 16 + quad * 4 + rr;
      if (row < M){
        u16* crow = C + qoff + (size_t)row * 64;
        #pragma unroll
        for (int j = 0; j < 4; j++)
          __builtin_nontemporal_store(f2bf(acc[i][j][rr]), crow + j * 16 + ml);
      }
    }
  }
}

// ---------------- count: per-(dst, src-quarter) degree + per-edge rank
__global__ __launch_bounds__(256) void count_k(const int* __restrict__ dst,
                                               const int* __restrict__ src,
                                               int* __restrict__ deg4,
                                               int* __restrict__ epos){
  int e = blockIdx.x * 256 + threadIdx.x;
  if (e < NE){
    int v = dst[e] * 4 + (src[e] >> SQSH);
    epos[e] = atomicAdd(&deg4[v], 1);
  }
}

// ---------------- scan NV=200k bucket degrees -> local offsets + block sums
__global__ __launch_bounds__(256) void scan1_k(const int* __restrict__ deg4,
                                               int* __restrict__ offs4,
                                               int* __restrict__ bsum){
  __shared__ int lds[256];
  int b = blockIdx.x, tid = threadIdx.x;
  int base = b * 1024 + tid * 4;
  int d[4]; int tsum = 0;
  #pragma unroll
  for (int j = 0; j < 4; j++){
    int v = (base + j < NV) ? deg4[base + j] : 0;
    d[j] = tsum; tsum += v;
  }
  lds[tid] = tsum; __syncthreads();
  for (int off = 1; off < 256; off <<= 1){
    int v = (tid >= off) ? lds[tid - off] : 0;
    __syncthreads();
    lds[tid] += v;
    __syncthreads();
  }
  int excl = lds[tid] - tsum;
  #pragma unroll
  for (int j = 0; j < 4; j++)
    if (base + j < NV) offs4[base + j] = excl + d[j];
  if (tid == 255) bsum[b] = lds[tid];
}

// 256-wide scan over up to 256 block sums (NV/1024 = 196 blocks)
__global__ __launch_bounds__(256) void scan2_k(const int* __restrict__ bsum,
                                               int* __restrict__ bbase, int nb){
  __shared__ int l[256];
  int tid = threadIdx.x;
  int v = (tid < nb) ? bsum[tid] : 0;
  l[tid] = v; __syncthreads();
  for (int off = 1; off < 256; off <<= 1){
    int u = (tid >= off) ? l[tid - off] : 0;
    __syncthreads();
    l[tid] += u;
    __syncthreads();
  }
  bbase[tid] = l[tid] - v;
}

// ---------------- scatter edges into src-bucketed CSR (NO atomics)
// csr entry = (src << 7) | etype. Within a node's segment, edges are grouped
// by src-quarter -> agg's sequential sweep walks 2.1MB gather regions in order.
__global__ __launch_bounds__(256) void scatter_k(const int* __restrict__ dst,
                                                 const int* __restrict__ src,
                                                 const int* __restrict__ ef,
                                                 const int* __restrict__ epos,
                                                 const int* __restrict__ offs4,
                                                 const int* __restrict__ bbase4,
                                                 int* __restrict__ csr){
  int e = blockIdx.x * 256 + threadIdx.x;
  if (e >= NE) return;
  int sv = src[e];
  int v = dst[e] * 4 + (sv >> SQSH);
  int pos = offs4[v] + bbase4[v >> 10] + epos[e];
  csr[pos] = (sv << 7) | ef[e];
}

// ---------------- attn output: attn[e,h] = wl[type,h] * rdq[h>>1][dst][h&1]
__global__ __launch_bounds__(256) void attn_k(const int* __restrict__ dst,
                                              const int* __restrict__ ef,
                                              const float* __restrict__ rdq,
                                              const float* __restrict__ emb,
                                              float* __restrict__ attn){
  __shared__ float wl[40];
  int tid = threadIdx.x;
  if (tid < 40){
    int t = tid >> 3, h = tid & 7;
    float m = emb[h];
    for (int tt = 1; tt < NTY; ++tt) m = fmaxf(m, emb[tt * 8 + h]);
    wl[tid] = expf(emb[t * 8 + h] - m);
  }
  __syncthreads();
  int e = blockIdx.x * 256 + tid;
  if (e >= NE) return;
  int d = dst[e], t = ef[e];
  const float* wr = wl + t * 8;
  f32x4 o0, o1;
  #pragma unroll
  for (int q = 0; q < 4; q++){
    float2 rv = *(const float2*)(rdq + ((size_t)q * NND + d) * 2);
    float a = wr[2 * q] * rv.x, b = wr[2 * q + 1] * rv.y;
    if (q < 2){ o0[2 * q] = a; o0[2 * q + 1] = b; }
    else      { o1[2 * (q - 2)] = a; o1[2 * (q - 2) + 1] = b; }
  }
  __builtin_nontemporal_store(o0, (f32x4*)(attn + (size_t)e * 8));
  __builtin_nontemporal_store(o1, (f32x4*)(attn + (size_t)e * 8 + 4));
}

// ---------------- aggregation: rst = (Σ w·fsrc) / (Σ w), rd cancels.
// Round-2 request shape (8 lanes/node x 16B = ONE 128B line per edge-pass =
// the line-request floor; round 3's 64B rows doubled requests and lost 71%).
// NEW: (a) XCD-pinned pair-quarters -- XCD c=blockIdx&7 handles quarter c>>1
// only (pinning mechanism verified by round-3 FETCH drop), halving the
// XCD-phases per region; (b) csr is src-quarter-bucketed, so the sequential
// [s,e) sweep visits gather regions of 2.1MB in order -> instantaneous L2
// working set fits 4MB. Stores non-temporal (keep L2 for the gather).
__device__ inline void acc8(uint4 v, float wt, f32x2* a){
  f32x2 w2; w2.x = wt; w2.y = wt;
  f32x2 t0; t0.x = __uint_as_float(v.x << 16); t0.y = __uint_as_float(v.x & 0xFFFF0000u);
  f32x2 t1; t1.x = __uint_as_float(v.y << 16); t1.y = __uint_as_float(v.y & 0xFFFF0000u);
  f32x2 t2; t2.x = __uint_as_float(v.z << 16); t2.y = __uint_as_float(v.z & 0xFFFF0000u);
  f32x2 t3; t3.x = __uint_as_float(v.w << 16); t3.y = __uint_as_float(v.w & 0xFFFF0000u);
  a[0] += w2 * t0; a[1] += w2 * t1; a[2] += w2 * t2; a[3] += w2 * t3;
}

#define NBLK ((NND + 31) / 32)            // 1563 node-blocks per quarter
#define NBH  ((NBLK + 1) / 2)             // 782: node-blocks per (quarter, xcd-half)

__global__ __launch_bounds__(256) void agg_k(const u16* __restrict__ fsrc,
                                             const int* __restrict__ csr,
                                             const int* __restrict__ offs4,
                                             const int* __restrict__ bbase4,
                                             const int* __restrict__ deg4,
                                             const float* __restrict__ emb,
                                             float* __restrict__ rst,
                                             float* __restrict__ rdq){
  __shared__ float wl[40];
  int tid = threadIdx.x;
  if (tid < 40){
    int t = tid >> 3, h = tid & 7;
    float m = emb[h];
    for (int tt = 1; tt < NTY; ++tt) m = fmaxf(m, emb[tt * 8 + h]);
    wl[tid] = expf(emb[t * 8 + h] - m);
  }
  __syncthreads();
  const int c  = blockIdx.x & 7;        // XCD (HW round-robin)
  const int q  = c >> 1;                // pair-quarter pinned to XCD pair
  const int nb = (blockIdx.x >> 3) * 2 + (c & 1);
  int node = nb * 32 + (tid >> 3);
  if (node >= NND) return;
  const int sl = tid & 7;               // 8 lanes/node, 16B each = 128B line
  const int h  = 2 * q + (sl >> 2);     // head this lane accumulates
  const u16* qbase = fsrc + (size_t)q * (NND * 64) + sl * 8;
  const int v0 = node * 4;
  int s = offs4[v0] + bbase4[v0 >> 10];
  int4 dg = *(const int4*)(deg4 + v0);  // 16B-aligned: v0 = 4*node
  int e = s + dg.x + dg.y + dg.z + dg.w;
  f32x2 a[4]; a[0] = 0.f; a[1] = 0.f; a[2] = 0.f; a[3] = 0.f;
  float ss = 0.f;
  int i = s;
  for (; i + 3 < e; i += 4){
    int p0 = csr[i], p1 = csr[i+1], p2 = csr[i+2], p3 = csr[i+3];
    uint4 v0g = *(const uint4*)(qbase + ((size_t)(p0 >> 7) << 6));
    uint4 v1g = *(const uint4*)(qbase + ((size_t)(p1 >> 7) << 6));
    uint4 v2g = *(const uint4*)(qbase + ((size_t)(p2 >> 7) << 6));
    uint4 v3g = *(const uint4*)(qbase + ((size_t)(p3 >> 7) << 6));
    float w0 = wl[(p0 & 7) * 8 + h];
    float w1 = wl[(p1 & 7) * 8 + h];
    float w2 = wl[(p2 & 7) * 8 + h];
    float w3 = wl[(p3 & 7) * 8 + h];
    acc8(v0g, w0, a); acc8(v1g, w1, a); acc8(v2g, w2, a); acc8(v3g, w3, a);
    ss += (w0 + w1) + (w2 + w3);
  }
  for (; i < e; i++){
    int p0 = csr[i];
    uint4 v0g = *(const uint4*)(qbase + ((size_t)(p0 >> 7) << 6));
    float w0 = wl[(p0 & 7) * 8 + h];
    acc8(v0g, w0, a);
    ss += w0;
  }
  float inv = 1.0f / (ss + 1e-12f);
  f32x4 o0, o1;
  o0[0] = a[0].x*inv; o0[1] = a[0].y*inv; o0[2] = a[1].x*inv; o0[3] = a[1].y*inv;
  o1[0] = a[2].x*inv; o1[1] = a[2].y*inv; o1[2] = a[3].x*inv; o1[3] = a[3].y*inv;
  float* orow = rst + (size_t)node * 256 + q * 64 + sl * 8;
  __builtin_nontemporal_store(o0, (f32x4*)orow);
  __builtin_nontemporal_store(o1, (f32x4*)(orow + 4));
  // rdq for attn_k: one lane per (node, head-within-quarter). deg0 never read.
  if ((sl & 3) == 0)
    __builtin_nontemporal_store(inv, rdq + ((size_t)q * NND + node) * 2 + (sl >> 2));
}

extern "C" void kernel_launch(void* const* d_in, const int* in_sizes, int n_in,
                              void* d_out, int out_size, void* d_ws, size_t ws_size,
                              hipStream_t stream) {
  const float* feat = (const float*)d_in[0];
  const float* fcw  = (const float*)d_in[1];
  const float* emb  = (const float*)d_in[2];
  const int*   ef   = (const int*)d_in[3];
  const int*   src  = (const int*)d_in[4];
  const int*   dst  = (const int*)d_in[5];

  float* rst  = (float*)d_out;                         // [50000, 8, 32]
  float* attn = (float*)d_out + (size_t)NND * NH * ND; // [800000, 8]

  char* ws = (char*)d_ws;
  size_t o = 0;
  u16* fsrc    = (u16*)(ws + o);   o += (size_t)NND * 256 * 2;   // 25.6 MB (pair-quarter-major)
  int* csr     = (int*)(ws + o);   o += (size_t)NE * 4;          // 3.2 MB
  int* epos    = (int*)(ws + o);   o += (size_t)NE * 4;          // 3.2 MB
  int* offs4   = (int*)(ws + o);   o += (size_t)NV * 4 + 256;    // 800 KB
  int* deg4    = (int*)(ws + o);   o += (size_t)NV * 4 + 256;    // 800 KB
  float* rdq   = (float*)(ws + o); o += (size_t)NND * NH * 4;    // 1.6 MB [4][NND][2]
  u16* wb      = (u16*)(ws + o);   o += (size_t)256 * 256 * 2;   // 128 KB
  int* bsum    = (int*)(ws + o);   o += 1024;                    // 256 ints
  int* bbase4  = (int*)(ws + o);   o += 1024;                    // 256 ints

  hipMemsetAsync(deg4, 0, (size_t)NV * 4, stream);

  wcvt_k<<<64, 256, 0, stream>>>(fcw, wb);
  gemm_k<<<391, 512, 0, stream>>>(feat, wb, fsrc, NND);
  count_k<<<(NE + 255) / 256, 256, 0, stream>>>(dst, src, deg4, epos);
  scan1_k<<<(NV + 1023) / 1024, 256, 0, stream>>>(deg4, offs4, bsum);
  scan2_k<<<1, 256, 0, stream>>>(bsum, bbase4, (NV + 1023) / 1024);
  scatter_k<<<(NE + 255) / 256, 256, 0, stream>>>(dst, src, ef, epos, offs4, bbase4, csr);
  agg_k<<<8 * NBH, 256, 0, stream>>>(fsrc, csr, offs4, bbase4, deg4, emb, rst, rdq);
  attn_k<<<(NE + 255) / 256, 256, 0, stream>>>(dst, ef, rdq, emb, attn);
}